// Round 4
// baseline (792.701 us; speedup 1.0000x reference)
//
#include <hip/hip_runtime.h>

// B=64, S=1024, D=800, MS=16, T=32, H=200, NS=12
// Nseq=1024, M=32768 (m = t*1024 + seq). GEMM N=1664 (2 dirs x 800, pad 64).
// Z layout per dir: [m][832] bf16, col = u*4 + gate (u padded 200->208).
// WhhP2: [dir(2)][gate(4)][u_pad 208][k_pad 224] bf16 rows: row = dir*832+gate*208+u.

typedef __attribute__((ext_vector_type(4))) float f32x4;
typedef __attribute__((ext_vector_type(8))) short s16x8;

__device__ __forceinline__ unsigned short f2bf(float f) {
    union { float f; unsigned int u; } a; a.f = f;
    unsigned int u = a.u;
    u += 0x7fffu + ((u >> 16) & 1u);   // RNE
    return (unsigned short)(u >> 16);
}
__device__ __forceinline__ float bf2f(unsigned short s) {
    union { unsigned int u; float f; } a; a.u = ((unsigned int)s) << 16; return a.f;
}
__device__ __forceinline__ void async_copy16(const void* g, void* l) {
    __builtin_amdgcn_global_load_lds(
        (const __attribute__((address_space(1))) unsigned int*)g,
        (__attribute__((address_space(3))) unsigned int*)l, 16, 0, 0);
}
__device__ __forceinline__ float sigf_(float x) {
    return 1.f / (1.f + __expf(-x));
}
__device__ __forceinline__ float tanhf_(float x) {
    float ax = fabsf(x);
    float e = __expf(-2.f * ax);
    float r = (1.f - e) / (1.f + e);
    return x < 0.f ? -r : r;
}

// ---------------- kernel 1: pack weights ----------------
__global__ void pack_kernel(const float* __restrict__ Wih_f, const float* __restrict__ Wih_b,
                            const float* __restrict__ Whh_f, const float* __restrict__ Whh_b,
                            const float* __restrict__ bih_f, const float* __restrict__ bhh_f,
                            const float* __restrict__ bih_b, const float* __restrict__ bhh_b,
                            unsigned short* __restrict__ Wp, unsigned short* __restrict__ WhhP2,
                            float* __restrict__ biasP)
{
    int tid = blockIdx.x * blockDim.x + threadIdx.x;
    if (tid < 1664 * 800) {
        int n = tid / 800, k = tid - n * 800;
        float v = 0.f;
        if (n < 800)       v = Wih_f[n * 800 + k];
        else if (n < 1600) v = Wih_b[(n - 800) * 800 + k];
        Wp[tid] = f2bf(v);
        return;
    }
    int t2 = tid - 1664 * 800;
    if (t2 < 1664 * 224) {
        int row = t2 / 224, k = t2 - row * 224;
        int d = row >= 832;
        int rg = row - d * 832;
        int gate = rg / 208;
        int u = rg - gate * 208;
        float v = 0.f;
        if (u < 200 && k < 200)
            v = (d ? Whh_b : Whh_f)[(gate * 200 + u) * 200 + k];
        WhhP2[t2] = f2bf(v);
        return;
    }
    int t3 = t2 - 1664 * 224;
    if (t3 < 1664) {
        float v = 0.f;
        if (t3 < 800)       v = bih_f[t3] + bhh_f[t3];
        else if (t3 < 1600) v = bih_b[t3 - 800] + bhh_b[t3 - 800];
        biasP[t3] = v;
    }
}

// ---------------- kernel 2: gather spans + fp32->bf16 ----------------
// Xg row m = t*1024 + seq
__global__ void gather_kernel(const float* __restrict__ hidden, const int* __restrict__ starts,
                              unsigned short* __restrict__ Xg)
{
    int tid = blockIdx.x * blockDim.x + threadIdx.x;   // one per 4 elements
    if (tid >= 32768 * 200) return;
    int row = tid / 200;
    int c4  = tid - row * 200;
    int t   = row >> 10, seq = row & 1023;
    int b   = seq >> 4;
    int src = starts[seq] + t;
    src = src < 1023 ? src : 1023;
    const float4 v = *(const float4*)(hidden + (size_t)(b * 1024 + src) * 800 + c4 * 4);
    ushort4 o;
    o.x = f2bf(v.x); o.y = f2bf(v.y); o.z = f2bf(v.z); o.w = f2bf(v.w);
    *(ushort4*)(Xg + (size_t)row * 800 + c4 * 4) = o;
}

// ---------------- kernel 3: GEMM Z = Xg @ Wp^T + bias ----------------
// Epilogue scatters to Zf/Zb[m][u*4+gate].
__global__ __launch_bounds__(256) void gemm_kernel(const unsigned short* __restrict__ Xg,
                                                   const unsigned short* __restrict__ Wp,
                                                   const float* __restrict__ biasP,
                                                   unsigned short* __restrict__ Zf,
                                                   unsigned short* __restrict__ Zb)
{
    __shared__ __align__(16) unsigned short As[128 * 32];
    __shared__ __align__(16) unsigned short Bs[128 * 32];
    const int tid = threadIdx.x;
    const int wid = tid >> 6, lane = tid & 63;
    const int m0 = blockIdx.x * 128;
    const int n0 = blockIdx.y * 128;
    const int wm = (wid >> 1) * 64, wn = (wid & 1) * 64;
    const int l15 = lane & 15, l4 = lane >> 4;

    f32x4 acc[4][4];
#pragma unroll
    for (int i = 0; i < 4; i++)
#pragma unroll
        for (int j = 0; j < 4; j++) acc[i][j] = (f32x4){0.f, 0.f, 0.f, 0.f};

    const int r0 = tid >> 2,         kc0 = (tid & 3) * 8;
    const int r1 = (256 + tid) >> 2, kc1 = (tid & 3) * 8;
    unsigned short* AsB0 = As + (size_t)(wid * 64) * 8;
    unsigned short* AsB1 = As + (size_t)(256 + wid * 64) * 8;
    unsigned short* BsB0 = Bs + (size_t)(wid * 64) * 8;
    unsigned short* BsB1 = Bs + (size_t)(256 + wid * 64) * 8;

    for (int kb = 0; kb < 25; ++kb) {
        const int kk = kb * 32;
        async_copy16(Xg + (size_t)(m0 + r0) * 800 + kk + kc0, AsB0);
        async_copy16(Xg + (size_t)(m0 + r1) * 800 + kk + kc1, AsB1);
        async_copy16(Wp + (size_t)(n0 + r0) * 800 + kk + kc0, BsB0);
        async_copy16(Wp + (size_t)(n0 + r1) * 800 + kk + kc1, BsB1);
        __syncthreads();

        s16x8 a[4], b[4];
#pragma unroll
        for (int i = 0; i < 4; i++)
            a[i] = *(const s16x8*)(As + (wm + i * 16 + l15) * 32 + l4 * 8);
#pragma unroll
        for (int i = 0; i < 4; i++)
            b[i] = *(const s16x8*)(Bs + (wn + i * 16 + l15) * 32 + l4 * 8);
#pragma unroll
        for (int im = 0; im < 4; im++)
#pragma unroll
            for (int in = 0; in < 4; in++)
                acc[im][in] = __builtin_amdgcn_mfma_f32_16x16x32_bf16(a[im], b[in], acc[im][in], 0, 0, 0);
        __syncthreads();
    }

    float bias_v[4];
#pragma unroll
    for (int in = 0; in < 4; in++) bias_v[in] = biasP[n0 + wn + in * 16 + l15];

#pragma unroll
    for (int im = 0; im < 4; im++) {
        int mbase = m0 + wm + im * 16 + l4 * 4;
#pragma unroll
        for (int in = 0; in < 4; in++) {
            int col = n0 + wn + in * 16 + l15;
            if (col < 1600) {
                int d = col >= 800;
                int cg = col - d * 800;
                int gate = (cg >= 600) ? 3 : (cg >= 400) ? 2 : (cg >= 200) ? 1 : 0;
                int u = cg - gate * 200;
                int zcol = u * 4 + gate;
                unsigned short* Zd = d ? Zb : Zf;
#pragma unroll
                for (int r = 0; r < 4; r++)
                    Zd[(size_t)(mbase + r) * 832 + zcol] = f2bf(acc[im][in][r] + bias_v[in]);
            }
        }
    }
}

// ---------------- kernel 4: masked bidirectional LSTM + pooled feats ----------------
// 256 blocks x 256 threads (4 waves): dir = bx>>7, g8 = bx&127 -> 8 sequences (m=8).
// Gates live in MFMA C-fragments per lane (4 accs/unit-tile) -> gate math fully in
// registers, ONE barrier/step, h double-buffered in LDS. Whh unit-tiles {w,4+w}
// register-resident; {8+w} (+{12} for w3) streamed from L2 per step.
__global__ __launch_bounds__(256, 1) void lstm_kernel(const unsigned short* __restrict__ Zf,
                                                      const unsigned short* __restrict__ Zb,
                                                      const unsigned short* __restrict__ WhhP2,
                                                      const int* __restrict__ span_lens,
                                                      float* __restrict__ feats)
{
    __shared__ __align__(16) unsigned short h2[2][16 * 232];    // A operand, k pad 224, stride 232
    __shared__ __align__(16) unsigned short zbuf[2][8 * 832];   // staged input-z tiles (bf16)

    const int bx = blockIdx.x;
    const int dir = bx >> 7;
    const int g8 = bx & 127;
    const int seq0 = g8 * 8;
    const int tid = threadIdx.x;
    const int w = tid >> 6, lane = tid & 63;
    const int l15 = lane & 15, l4 = lane >> 4;
    const unsigned short* __restrict__ Zd = dir ? Zb : Zf;

    for (int i = tid; i < 2 * 16 * 232; i += 256) ((unsigned short*)h2)[i] = 0;

    // ---- register-resident Whh tiles: ut = q*4 + w for q in {0,1}
    s16x8 breg[2][4][7];
#pragma unroll
    for (int q = 0; q < 2; ++q)
#pragma unroll
        for (int gate = 0; gate < 4; ++gate) {
            const int row = dir * 832 + gate * 208 + (q * 4 + w) * 16 + l15;
            const unsigned short* wp = WhhP2 + (size_t)row * 224 + l4 * 8;
#pragma unroll
            for (int kk = 0; kk < 7; ++kk)
                breg[q][gate][kk] = *(const s16x8*)(wp + kk * 32);
        }
    const int ut2 = 8 + w;   // streamed tile (all waves); wave 3 also streams ut=12

    // ---- per-lane state: slots 0..3 (slot3 = ut12, wave 3 only), component r -> s=l4*4+r
    f32x4 cst[4], fst[4];
    unsigned short hr[4][4];
#pragma unroll
    for (int q = 0; q < 4; ++q) {
        cst[q] = (f32x4){0.f, 0.f, 0.f, 0.f};
        fst[q] = (f32x4){0.f, 0.f, 0.f, 0.f};
#pragma unroll
        for (int r = 0; r < 4; ++r) hr[q][r] = 0;
    }
    int len4[4];
    {
        int sbase = (l4 < 2 ? l4 : 1) * 4;
#pragma unroll
        for (int r = 0; r < 4; ++r) len4[r] = span_lens[seq0 + sbase + r];
    }

    // ---- prefetch step-0 tile into zbuf[0] (13 chunks of 1 KiB)
    {
        const int t0 = dir ? 31 : 0;
        const unsigned short* gb = Zd + (size_t)(t0 * 1024 + seq0) * 832;
        for (int c = w; c < 13; c += 4)
            async_copy16(gb + c * 512 + lane * 8, (unsigned short*)zbuf[0] + c * 512);
    }
    __syncthreads();

    for (int step = 0; step < 32; ++step) {
        const int t = dir ? (31 - step) : step;
        const int cur = step & 1, nxt = cur ^ 1;
        if (step < 31) {
            const int tn = dir ? (t - 1) : (t + 1);
            const unsigned short* gb = Zd + (size_t)(tn * 1024 + seq0) * 832;
            for (int c = w; c < 13; c += 4)
                async_copy16(gb + c * 512 + lane * 8, (unsigned short*)zbuf[nxt] + c * 512);
        }

        // ---- phase 1: gate pre-activations via MFMA, accs stay in this wave
        s16x8 afr[7];
        {
            const unsigned short* hrow = h2[cur] + l15 * 232 + l4 * 8;
#pragma unroll
            for (int kk = 0; kk < 7; ++kk)
                afr[kk] = *(const s16x8*)(hrow + kk * 32);
        }
        f32x4 accA[2][4];
#pragma unroll
        for (int q = 0; q < 2; ++q)
#pragma unroll
            for (int gate = 0; gate < 4; ++gate) {
                f32x4 a = (f32x4){0.f, 0.f, 0.f, 0.f};
#pragma unroll
                for (int kk = 0; kk < 7; ++kk)
                    a = __builtin_amdgcn_mfma_f32_16x16x32_bf16(afr[kk], breg[q][gate][kk], a, 0, 0, 0);
                accA[q][gate] = a;
            }
        f32x4 accS[4];
#pragma unroll
        for (int gate = 0; gate < 4; ++gate) {
            const int row = dir * 832 + gate * 208 + ut2 * 16 + l15;
            const unsigned short* wp = WhhP2 + (size_t)row * 224 + l4 * 8;
            s16x8 bs[7];
#pragma unroll
            for (int kk = 0; kk < 7; ++kk)
                bs[kk] = *(const s16x8*)(wp + kk * 32);
            f32x4 a = (f32x4){0.f, 0.f, 0.f, 0.f};
#pragma unroll
            for (int kk = 0; kk < 7; ++kk)
                a = __builtin_amdgcn_mfma_f32_16x16x32_bf16(afr[kk], bs[kk], a, 0, 0, 0);
            accS[gate] = a;
        }
        f32x4 acc12[4];
        if (w == 3) {
#pragma unroll
            for (int gate = 0; gate < 4; ++gate) {
                const int row = dir * 832 + gate * 208 + 12 * 16 + l15;
                const unsigned short* wp = WhhP2 + (size_t)row * 224 + l4 * 8;
                s16x8 bs[7];
#pragma unroll
                for (int kk = 0; kk < 7; ++kk)
                    bs[kk] = *(const s16x8*)(wp + kk * 32);
                f32x4 a = (f32x4){0.f, 0.f, 0.f, 0.f};
#pragma unroll
                for (int kk = 0; kk < 7; ++kk)
                    a = __builtin_amdgcn_mfma_f32_16x16x32_bf16(afr[kk], bs[kk], a, 0, 0, 0);
                acc12[gate] = a;
            }
        }

        // ---- phase 2: gate math in registers (rows s = l4*4+r, valid s<8)
        if (l4 < 2) {
            const unsigned short* zc = zbuf[cur];
            unsigned short* h2n = h2[nxt];
#pragma unroll
            for (int qq = 0; qq < 4; ++qq) {
                if (qq == 3 && w != 3) continue;     // slot3 only on wave 3
                const int ut = (qq == 0) ? (0 * 4 + w) : (qq == 1) ? (1 * 4 + w)
                             : (qq == 2) ? ut2 : 12;
                const f32x4* ag = (qq == 0) ? accA[0] : (qq == 1) ? accA[1]
                                : (qq == 2) ? accS : acc12;
                const int ucol = ut * 16 + l15;
#pragma unroll
                for (int r = 0; r < 4; ++r) {
                    const int s = l4 * 4 + r;
                    const int live = (t < len4[r]);
                    ushort4 zb4 = *(const ushort4*)(zc + s * 832 + ucol * 4);
                    float zi = ag[0][r] + bf2f(zb4.x);
                    float zf = ag[1][r] + bf2f(zb4.y);
                    float zg = ag[2][r] + bf2f(zb4.z);
                    float zo = ag[3][r] + bf2f(zb4.w);
                    float cn = sigf_(zf) * cst[qq][r] + sigf_(zi) * tanhf_(zg);
                    float hn = sigf_(zo) * tanhf_(cn);
                    if (live) {
                        cst[qq][r] = cn;
                        fst[qq][r] += hn;
                        hr[qq][r] = f2bf(hn);
                    }
                    h2n[s * 232 + ucol] = hr[qq][r];
                }
            }
        }
        __syncthreads();   // h2[nxt] complete; zbuf[nxt] DMA drained; zbuf[cur] free
    }

    // ---- store pooled feats
    if (l4 < 2) {
#pragma unroll
        for (int qq = 0; qq < 4; ++qq) {
            if (qq == 3 && w != 3) continue;
            const int ut = (qq == 0) ? (0 * 4 + w) : (qq == 1) ? (1 * 4 + w)
                         : (qq == 2) ? ut2 : 12;
            const int u = ut * 16 + l15;
            if (u < 200) {
#pragma unroll
                for (int r = 0; r < 4; ++r) {
                    const int s = l4 * 4 + r;
                    feats[(size_t)(seq0 + s) * 400 + dir * 200 + u] = fst[qq][r];
                }
            }
        }
    }
}

// ---------------- kernel 5: logits = feats @ slot_embs * slot_mask ----------------
__global__ void logits_kernel(const float* __restrict__ feats, const float* __restrict__ se,
                              const float* __restrict__ slot_mask, float* __restrict__ out)
{
    int tid = blockIdx.x * blockDim.x + threadIdx.x;
    if (tid >= 1024 * 12) return;
    int n = tid / 12, ns = tid - n * 12;
    const float* f = feats + (size_t)n * 400;
    float acc = 0.f;
    for (int u = 0; u < 400; ++u) acc += f[u] * se[u * 12 + ns];
    out[tid] = acc * slot_mask[n];
}

extern "C" void kernel_launch(void* const* d_in, const int* in_sizes, int n_in,
                              void* d_out, int out_size, void* d_ws, size_t ws_size,
                              hipStream_t stream)
{
    const float* hidden      = (const float*)d_in[0];
    const float* Wih_f       = (const float*)d_in[1];
    const float* Whh_f       = (const float*)d_in[2];
    const float* bih_f       = (const float*)d_in[3];
    const float* bhh_f       = (const float*)d_in[4];
    const float* Wih_b       = (const float*)d_in[5];
    const float* Whh_b       = (const float*)d_in[6];
    const float* bih_b       = (const float*)d_in[7];
    const float* bhh_b       = (const float*)d_in[8];
    const float* slot_embs   = (const float*)d_in[9];
    const int*   span_starts = (const int*)d_in[10];
    const int*   span_lens   = (const int*)d_in[11];
    const float* slot_mask   = (const float*)d_in[12];
    float* out = (float*)d_out;

    char* ws = (char*)d_ws;
    unsigned short* Xg     = (unsigned short*)(ws + 0);           //  52,428,800
    unsigned short* Wp     = (unsigned short*)(ws + 52428800);    //   2,662,400
    unsigned short* WhhP2  = (unsigned short*)(ws + 55091200);    //     745,472 (1664 x 224 bf16)
    float*          biasP  = (float*)         (ws + 55836672);    //       6,656
    unsigned short* Zf     = (unsigned short*)(ws + 55843328);    //  54,525,952 (32768 x 832 bf16)
    unsigned short* Zb     = (unsigned short*)(ws + 110369280);   //  54,525,952
    float*          feats  = (float*)         (ws + 164895232);   //   1,638,400
    // total: 166,533,632 B

    {
        int total = 1664 * 800 + 1664 * 224 + 1664;
        int blocks = (total + 255) / 256;
        pack_kernel<<<blocks, 256, 0, stream>>>(Wih_f, Wih_b, Whh_f, Whh_b,
                                                bih_f, bhh_f, bih_b, bhh_b,
                                                Wp, WhhP2, biasP);
    }
    gather_kernel<<<25600, 256, 0, stream>>>(hidden, span_starts, Xg);
    gemm_kernel<<<dim3(256, 13), 256, 0, stream>>>(Xg, Wp, biasP, Zf, Zb);
    lstm_kernel<<<256, 256, 0, stream>>>(Zf, Zb, WhhP2, span_lens, feats);
    logits_kernel<<<48, 256, 0, stream>>>(feats, slot_embs, slot_mask, out);
}